// Round 16
// baseline (104.911 us; speedup 1.0000x reference)
//
#include <hip/hip_runtime.h>
#include <hip/hip_fp16.h>

// Problem constants (from reference): B=2, N=512, D=256, H=8, L=3
#define BB 2
#define NNq 512
#define DDm 256
#define HHh 8
#define DHh 32
#define LLn 3

static constexpr float EPSF   = 1e-4f;
static constexpr float INV2PI = 0.15915494309189535f;   // 1/(2*pi)
static constexpr float SCALE  = 0.17677669529663687f;   // 1/sqrt(32)

#if __has_builtin(__builtin_amdgcn_fractf)
#define FRACTF(x) __builtin_amdgcn_fractf(x)
#else
#define FRACTF(x) ((x) - floorf(x))
#endif
#if __has_builtin(__builtin_amdgcn_sinf)
#define SINR(x) __builtin_amdgcn_sinf(x)   // sin(2*pi*x), x in revolutions
#define COSR(x) __builtin_amdgcn_cosf(x)
#else
#define SINR(x) __sinf((x) * 6.2831853071795865f)
#define COSR(x) __cosf((x) * 6.2831853071795865f)
#endif
#if __has_builtin(__builtin_amdgcn_rcpf)
#define RCPF(x) __builtin_amdgcn_rcpf(x)
#else
#define RCPF(x) (1.0f / (x))
#endif

typedef _Float16 f16x8 __attribute__((ext_vector_type(8)));
typedef _Float16 f16x4 __attribute__((ext_vector_type(4)));
typedef _Float16 f16x2 __attribute__((ext_vector_type(2)));
typedef float    f32x4 __attribute__((ext_vector_type(4)));

__device__ inline f16x2 pk2(float a, float b) {
#if __has_builtin(__builtin_amdgcn_cvt_pkrtz)
    return __builtin_bit_cast(f16x2, __builtin_amdgcn_cvt_pkrtz(a, b));
#else
    f16x2 r; r[0] = (_Float16)a; r[1] = (_Float16)b; return r;
#endif
}
union U16x8 { f16x8 v; f16x2 h[4]; };

// ---------------------------------------------------------------- weight pre-convert
__global__ __launch_bounds__(256) void k_wcvt(const float* __restrict__ Wq,
        const float* __restrict__ Wk, const float* __restrict__ Wv,
        const float* __restrict__ Wo, _Float16* __restrict__ WT,
        const float* __restrict__ Wg, _Float16* __restrict__ WgTg) {
    __shared__ _Float16 t[64][72];
    const int tid = threadIdx.x;
    const int mat = blockIdx.z;
    if (mat == 12) {
        if (blockIdx.x == 0 && blockIdx.y == 0) {
            for (int idx = tid; idx < 32 * 256; idx += 256) {
                int n = idx >> 8, k = idx & 255;
                float w = (n < 24) ? Wg[(size_t)(n >> 3) * 2048 + (size_t)k * 8 + (n & 7)] : 0.f;
                WgTg[n * 256 + (k ^ ((n & 7) << 3))] = (_Float16)w;
            }
        }
        return;
    }
    const int l = mat >> 2, op = mat & 3;
    const float* W = (op == 0 ? Wq : op == 1 ? Wk : op == 2 ? Wv : Wo)
                     + (size_t)l * 65536;
    const int k0 = blockIdx.x * 64, n0 = blockIdx.y * 64;
    for (int u = tid; u < 64 * 16; u += 256) {
        int k = u >> 4, n4 = (u & 15) * 4;
        float4 w4 = *reinterpret_cast<const float4*>(&W[(size_t)(k0 + k) * 256 + n0 + n4]);
        t[n4 + 0][k] = (_Float16)w4.x; t[n4 + 1][k] = (_Float16)w4.y;
        t[n4 + 2][k] = (_Float16)w4.z; t[n4 + 3][k] = (_Float16)w4.w;
    }
    __syncthreads();
    for (int u = tid; u < 64 * 8; u += 256) {
        int n = u >> 3, kc = (u & 7) * 8;
        *reinterpret_cast<f16x8*>(&WT[((size_t)mat * 256 + n0 + n) * 256 + k0 + kc]) =
            *reinterpret_cast<const f16x8*>(&t[n][kc]);
    }
}

// ---------------------------------------------------------------- fused geo + qkv0
// Blocks 0..2047: geo. Blocks 2048..2431: layer-0 qkv GEMM (LDS-free).
// (Round-14 verified structure; round-15's V-pre-transpose REVERTED — the
// 1KB-strided 8B global stores cost more than the attn staging saved.)
__global__ __launch_bounds__(256, 4) void k_geo_qkv0(const float* __restrict__ boxes,
        const _Float16* __restrict__ WgTg, const float* __restrict__ bg,
        const float* __restrict__ divm, const int* __restrict__ maskp,
        __half* __restrict__ G,
        const float* __restrict__ feat, const _Float16* __restrict__ WT,
        const float* __restrict__ bq, const float* __restrict__ bk,
        const float* __restrict__ bv,
        _Float16* __restrict__ qb, _Float16* __restrict__ kb,
        _Float16* __restrict__ vb) {
    __shared__ __half obuf[4][24][68];   // geo part only (13 KB)

    const int tid  = threadIdx.x;
    const int lane = tid & 63;
    const int wid  = tid >> 6;
    const int ln15 = lane & 15;
    const int kgrp = lane >> 4;

    if ((int)blockIdx.x >= 2048) {
        // ---------------- qkv layer-0 (LDS-free) ----------------
        const int q = blockIdx.x - 2048;         // 0..383
        const int z = q >> 7;                    // 0..2
        const int rem = q & 127;
        const int m0 = (rem >> 2) * 32, n0 = (rem & 3) * 64;
        const _Float16* WTz = WT + (size_t)z * 65536;
        const float* bia = (z == 0) ? bq : (z == 1) ? bk : bv;
        _Float16* C = (z == 0) ? qb : (z == 1) ? kb : vb;

        const int mw   = (wid & 1) * 16;
        const int nsel = (wid >> 1) * 16;
        const int kfr  = kgrp * 8;

        const float* Arow = feat + (size_t)(m0 + mw + ln15) * 256;
        const _Float16* W0r = WTz + (size_t)(n0 + nsel + ln15) * 256;
        const _Float16* W1r = WTz + (size_t)(n0 + nsel + 32 + ln15) * 256;

        f32x4 acc[2] = {{0.f,0.f,0.f,0.f},{0.f,0.f,0.f,0.f}};
#pragma unroll
        for (int kc = 0; kc < 8; ++kc) {
            float4 a0 = *reinterpret_cast<const float4*>(Arow + kc * 32 + kfr);
            float4 a1 = *reinterpret_cast<const float4*>(Arow + kc * 32 + kfr + 4);
            U16x8 af;
            af.h[0] = pk2(a0.x, a0.y); af.h[1] = pk2(a0.z, a0.w);
            af.h[2] = pk2(a1.x, a1.y); af.h[3] = pk2(a1.z, a1.w);
            f16x8 b0 = *reinterpret_cast<const f16x8*>(W0r + kc * 32 + kfr);
            f16x8 b1 = *reinterpret_cast<const f16x8*>(W1r + kc * 32 + kfr);
            acc[0] = __builtin_amdgcn_mfma_f32_16x16x32_f16(af.v, b0, acc[0], 0, 0, 0);
            acc[1] = __builtin_amdgcn_mfma_f32_16x16x32_f16(af.v, b1, acc[1], 0, 0, 0);
        }
#pragma unroll
        for (int t = 0; t < 2; ++t) {
            const int col = n0 + nsel + t * 32 + ln15;
            const float bv_ = bia[col];
#pragma unroll
            for (int r = 0; r < 4; ++r) {
                const int row = m0 + mw + kgrp * 4 + r;
                C[(size_t)row * 256 + col] = (_Float16)fmaxf(acc[t][r] + bv_, 0.f);
            }
        }
        return;
    }

    // ---------------- geo ----------------
    float invd[8];
    {
        const float4* dv4 = reinterpret_cast<const float4*>(divm);
        float4 da = dv4[kgrp * 2], db = dv4[kgrp * 2 + 1];
        invd[0] = INV2PI / da.x; invd[1] = INV2PI / da.y;
        invd[2] = INV2PI / da.z; invd[3] = INV2PI / da.w;
        invd[4] = INV2PI / db.x; invd[5] = INV2PI / db.y;
        invd[6] = INV2PI / db.z; invd[7] = INV2PI / db.w;
    }
    const int n0 = ln15;
    const int n1 = 16 + ln15;
    const float bg0 = bg[n0];
    const float bg1 = (n1 < 24) ? bg[n1] : 0.f;

    const int mask  = (ln15 & 7) << 3;
    const int flip5 = mask & 32;
    const int kb_   = (kgrp << 3) ^ (mask & 24);
    const int base0 = n0 * 256 + kb_;
    const int base1 = n1 * 256 + kb_;

    f16x8 bS0[4], bC0[4], bS1[4], bC1[4];
#pragma unroll
    for (int kc2 = 0; kc2 < 4; ++kc2) {
        const int koffS = ((2 * kc2) * 32) ^ flip5;
        const int koffC = ((2 * kc2 + 1) * 32) ^ flip5;
        bS0[kc2] = *reinterpret_cast<const f16x8*>(&WgTg[base0 + koffS]);
        bC0[kc2] = *reinterpret_cast<const f16x8*>(&WgTg[base0 + koffC]);
        bS1[kc2] = *reinterpret_cast<const f16x8*>(&WgTg[base1 + koffS]);
        bC1[kc2] = *reinterpret_cast<const f16x8*>(&WgTg[base1 + koffC]);
    }

    const float4* boxes4 = reinterpret_cast<const float4*>(boxes);
    const size_t plane = (size_t)NNq * NNq;

    const int base4 = (blockIdx.x * 4 + wid) * 4;
#pragma unroll
    for (int it = 0; it < 4; ++it) {
        const int slab = base4 + it;
        const int p0 = slab << 4;
        const int b  = p0 >> 18;
        const int rem = p0 & (NNq * NNq - 1);
        const int i  = rem >> 9;
        const int j0 = rem & (NNq - 1);

        float4 Bi = boxes4[b * NNq + i];
        float4 Bj = boxes4[b * NNq + j0 + ln15];
        float cxi = 0.5f * (Bi.x + Bi.z), cyi = 0.5f * (Bi.y + Bi.w);
        float wi  = fmaxf(Bi.z - Bi.x, EPSF), hi = fmaxf(Bi.w - Bi.y, EPSF);
        float cxj = 0.5f * (Bj.x + Bj.z), cyj = 0.5f * (Bj.y + Bj.w);
        float wj  = fmaxf(Bj.z - Bj.x, EPSF), hj = fmaxf(Bj.w - Bj.y, EPSF);
        float rwj = RCPF(wj), rhj = RCPF(hj);
        float rel[4];
        rel[0] = __logf(fabsf(cxj - cxi) * rwj + EPSF);
        rel[1] = __logf(fabsf(cyj - cyi) * rhj + EPSF);
        rel[2] = __logf(wi * rwj + EPSF);
        rel[3] = __logf(hi * rhj + EPSF);

        f32x4 acc0 = {0.f, 0.f, 0.f, 0.f};
        f32x4 acc1 = {0.f, 0.f, 0.f, 0.f};

#pragma unroll
        for (int kc2 = 0; kc2 < 4; ++kc2) {
            const float rc = rel[kc2];
            U16x8 afs, afc;
#pragma unroll
            for (int jj = 0; jj < 4; ++jj) {
                float rv0 = FRACTF(rc * invd[2 * jj]);
                float rv1 = FRACTF(rc * invd[2 * jj + 1]);
                afs.h[jj] = pk2(SINR(rv0), SINR(rv1));
                afc.h[jj] = pk2(COSR(rv0), COSR(rv1));
            }
            acc0 = __builtin_amdgcn_mfma_f32_16x16x32_f16(afs.v, bS0[kc2], acc0, 0, 0, 0);
            acc0 = __builtin_amdgcn_mfma_f32_16x16x32_f16(afc.v, bC0[kc2], acc0, 0, 0, 0);
            acc1 = __builtin_amdgcn_mfma_f32_16x16x32_f16(afs.v, bS1[kc2], acc1, 0, 0, 0);
            acc1 = __builtin_amdgcn_mfma_f32_16x16x32_f16(afc.v, bC1[kc2], acc1, 0, 0, 0);
        }

#pragma unroll
        for (int r = 0; r < 4; ++r) {
            const int m = it * 16 + (kgrp << 2) + r;
            float g0 = fmaxf(acc0[r] + bg0, 0.f);
            obuf[wid][n0][m] = __float2half(g0);
            if (n1 < 24) {
                float g1 = fmaxf(acc1[r] + bg1, 0.f);
                obuf[wid][n1][m] = __float2half(g1);
            }
        }
    }
    __syncthreads();

    const int b_  = base4 >> 14;
    const int i_  = (base4 >> 5) & (NNq - 1);
    const int j0b = (base4 & 31) << 4;
    const int mv  = maskp[((size_t)b_ * NNq + i_) * NNq + j0b + lane];
    size_t obase = (size_t)b_ * plane + (size_t)i_ * NNq + j0b + lane;
#pragma unroll
    for (int t = 0; t < 24; ++t) {
        float g = __half2float(obuf[wid][t][lane]);
        float v = (mv != 0) ? (g + 1e-6f) : 0.0f;
        G[obase + (size_t)t * (BB * plane)] = __float2half(v);
    }
}

// ---------------------------------------------------------------- GEMM qkv (fp16 A, LDS-free)
__global__ __launch_bounds__(256) void k_gemm_qkv_h(const _Float16* __restrict__ A,
        const _Float16* __restrict__ WT0, const _Float16* __restrict__ WT1,
        const _Float16* __restrict__ WT2,
        const float* __restrict__ b0, const float* __restrict__ b1, const float* __restrict__ b2,
        _Float16* __restrict__ C0, _Float16* __restrict__ C1, _Float16* __restrict__ C2) {
    const _Float16* WTz = (blockIdx.z == 0) ? WT0 : (blockIdx.z == 1) ? WT1 : WT2;
    const float*    bia = (blockIdx.z == 0) ? b0 : (blockIdx.z == 1) ? b1 : b2;
    _Float16*       C   = (blockIdx.z == 0) ? C0 : (blockIdx.z == 1) ? C1 : C2;

    const int tid  = threadIdx.x;
    const int lane = tid & 63, wid = tid >> 6;
    const int ln15 = lane & 15, kgrp = lane >> 4;
    const int m0 = blockIdx.x * 32, n0 = blockIdx.y * 64;
    const int mw   = (wid & 1) * 16;
    const int nsel = (wid >> 1) * 16;
    const int kfr  = kgrp * 8;

    const _Float16* Arow = A + (size_t)(m0 + mw + ln15) * 256;
    const _Float16* W0r  = WTz + (size_t)(n0 + nsel + ln15) * 256;
    const _Float16* W1r  = WTz + (size_t)(n0 + nsel + 32 + ln15) * 256;

    f32x4 acc[2] = {{0.f,0.f,0.f,0.f},{0.f,0.f,0.f,0.f}};
#pragma unroll
    for (int kc = 0; kc < 8; ++kc) {
        f16x8 af = *reinterpret_cast<const f16x8*>(Arow + kc * 32 + kfr);
        f16x8 b0_ = *reinterpret_cast<const f16x8*>(W0r + kc * 32 + kfr);
        f16x8 b1_ = *reinterpret_cast<const f16x8*>(W1r + kc * 32 + kfr);
        acc[0] = __builtin_amdgcn_mfma_f32_16x16x32_f16(af, b0_, acc[0], 0, 0, 0);
        acc[1] = __builtin_amdgcn_mfma_f32_16x16x32_f16(af, b1_, acc[1], 0, 0, 0);
    }
#pragma unroll
    for (int t = 0; t < 2; ++t) {
        const int col = n0 + nsel + t * 32 + ln15;
        const float bv = bia[col];
#pragma unroll
        for (int r = 0; r < 4; ++r) {
            const int row = m0 + mw + kgrp * 4 + r;
            C[(size_t)row * 256 + col] = (_Float16)fmaxf(acc[t][r] + bv, 0.f);
        }
    }
}

// ---------------------------------------------------------------- GEMM o (LDS-free)
// Round-16: single-store variants. resid from fp32 (layer 0) or fp16 (1,2);
// output to fp16 xh (layers 0,1) or fp32 d_out (layer 2).
__global__ __launch_bounds__(256) void k_gemm_o(const _Float16* __restrict__ A,
        const _Float16* __restrict__ WT0, const float* __restrict__ bia,
        const float* __restrict__ residf, const _Float16* __restrict__ residh,
        float* __restrict__ Cf, _Float16* __restrict__ Ch) {
    const int tid  = threadIdx.x;
    const int lane = tid & 63, wid = tid >> 6;
    const int ln15 = lane & 15, kgrp = lane >> 4;
    const int m0 = blockIdx.x * 32, n0 = blockIdx.y * 64;
    const int mw   = (wid & 1) * 16;
    const int nsel = (wid >> 1) * 16;
    const int kfr  = kgrp * 8;

    const _Float16* Arow = A + (size_t)(m0 + mw + ln15) * 256;
    const _Float16* W0r  = WT0 + (size_t)(n0 + nsel + ln15) * 256;
    const _Float16* W1r  = WT0 + (size_t)(n0 + nsel + 32 + ln15) * 256;

    f32x4 acc[2] = {{0.f,0.f,0.f,0.f},{0.f,0.f,0.f,0.f}};
#pragma unroll
    for (int kc = 0; kc < 8; ++kc) {
        f16x8 af = *reinterpret_cast<const f16x8*>(Arow + kc * 32 + kfr);
        f16x8 b0_ = *reinterpret_cast<const f16x8*>(W0r + kc * 32 + kfr);
        f16x8 b1_ = *reinterpret_cast<const f16x8*>(W1r + kc * 32 + kfr);
        acc[0] = __builtin_amdgcn_mfma_f32_16x16x32_f16(af, b0_, acc[0], 0, 0, 0);
        acc[1] = __builtin_amdgcn_mfma_f32_16x16x32_f16(af, b1_, acc[1], 0, 0, 0);
    }
#pragma unroll
    for (int t = 0; t < 2; ++t) {
        const int col = n0 + nsel + t * 32 + ln15;
        const float bv = bia[col];
#pragma unroll
        for (int r = 0; r < 4; ++r) {
            const int row = m0 + mw + kgrp * 4 + r;
            float rv = residf ? residf[(size_t)row * 256 + col]
                              : (float)residh[(size_t)row * 256 + col];
            float o = fmaxf(acc[t][r] + bv, 0.f) + rv;
            if (Cf) Cf[(size_t)row * 256 + col] = o;
            else    Ch[(size_t)row * 256 + col] = (_Float16)o;
        }
    }
}

// ---------------------------------------------------------------- fused attention (MFMA v2, multiplicative geo)
// Round-14 verified structure (V transposed during LDS staging).
__global__ __launch_bounds__(256) void k_attn(const _Float16* __restrict__ q,
                                              const _Float16* __restrict__ kk,
                                              const _Float16* __restrict__ vv,
                                              const __half* __restrict__ G,
                                              _Float16* __restrict__ y, int l) {
    __shared__ _Float16 Kh[512 * 32];   // 32 KB, row j: 64B, swz ((j&7)<<4)
    __shared__ _Float16 VT[32 * 512];   // 32 KB, row d: 1KB, swz ((d&7)<<4)
    __shared__ _Float16 Ps[4][16 * 128];// 16 KB, per-wave, swz ((i&7)<<4)

    const int bh = blockIdx.y;
    const int b = bh >> 3, h = bh & 7;
    const int i0t = blockIdx.x * 16;

    const int tid  = threadIdx.x;
    const int lane = tid & 63, wid = tid >> 6;
    const int ln15 = lane & 15, kgrp = lane >> 4;

    for (int u = tid; u < 2048; u += 256) {
        int j = u >> 2, d8 = (u & 3) * 8;
        const size_t src = (size_t)(b * NNq + j) * DDm + h * DHh + d8;
        f16x8 kv = *reinterpret_cast<const f16x8*>(&kk[src]);
        *reinterpret_cast<f16x8*>(reinterpret_cast<char*>(Kh) +
            ((j * 64 + d8 * 2) ^ ((j & 7) << 4))) = kv;
        f16x8 v8 = *reinterpret_cast<const f16x8*>(&vv[src]);
#pragma unroll
        for (int e = 0; e < 8; ++e) {
            int row = d8 + e;
            *reinterpret_cast<_Float16*>(reinterpret_cast<char*>(VT) +
                ((row * 1024 + j * 2) ^ ((row & 7) << 4))) = v8[e];
        }
    }

    f16x8 qf = *reinterpret_cast<const f16x8*>(
        &q[(size_t)(b * NNq + i0t + ln15) * DDm + h * DHh + kgrp * 8]);
    __syncthreads();

    const int jbase = wid * 128;
    const size_t plane = (size_t)NNq * NNq;
    const size_t g_base = (size_t)((l * 8 + h) * BB + b) * plane;

    f32x4 s[8];
#pragma unroll
    for (int t = 0; t < 8; ++t) {
        int j = jbase + t * 16 + ln15;
        f16x8 kf = *reinterpret_cast<const f16x8*>(reinterpret_cast<char*>(Kh) +
            ((j * 64 + kgrp * 16) ^ ((j & 7) << 4)));
        f32x4 z = {0.f, 0.f, 0.f, 0.f};
        s[t] = __builtin_amdgcn_mfma_f32_16x16x32_f16(qf, kf, z, 0, 0, 0);
    }

    float gv[8][4];
#pragma unroll
    for (int t = 0; t < 8; ++t) {
        const size_t jg = jbase + t * 16 + ln15;
#pragma unroll
        for (int r = 0; r < 4; ++r)
            gv[t][r] = __half2float(G[g_base + (size_t)(i0t + kgrp * 4 + r) * NNq + jg]);
    }

    float m_[4], l_[4];
#pragma unroll
    for (int r = 0; r < 4; ++r) {
        float mx = s[0][r];
#pragma unroll
        for (int t = 1; t < 8; ++t) mx = fmaxf(mx, s[t][r]);
        mx *= SCALE;
#pragma unroll
        for (int o = 1; o < 16; o <<= 1) mx = fmaxf(mx, __shfl_xor(mx, o, 64));
        float sum = 0.f;
#pragma unroll
        for (int t = 0; t < 8; ++t) {
            float p = gv[t][r] * __expf(s[t][r] * SCALE - mx);
            s[t][r] = p; sum += p;
        }
#pragma unroll
        for (int o = 1; o < 16; o <<= 1) sum += __shfl_xor(sum, o, 64);
        m_[r] = mx; l_[r] = sum;
    }

    {
        char* psb = reinterpret_cast<char*>(Ps[wid]);
#pragma unroll
        for (int r = 0; r < 4; ++r) {
            const int row = kgrp * 4 + r;
            const int rb = row * 256, sw = (row & 7) << 4;
#pragma unroll
            for (int t = 0; t < 8; ++t) {
                int byte = (rb + (t * 16 + ln15) * 2) ^ sw;
                *reinterpret_cast<_Float16*>(psb + byte) = (_Float16)s[t][r];
            }
        }
    }

    f32x4 oacc[2] = {{0.f,0.f,0.f,0.f},{0.f,0.f,0.f,0.f}};
    {
        char* psb = reinterpret_cast<char*>(Ps[wid]);
#pragma unroll
        for (int kc = 0; kc < 4; ++kc) {
            f16x8 pf = *reinterpret_cast<const f16x8*>(psb +
                ((ln15 * 256 + kc * 64 + kgrp * 16) ^ ((ln15 & 7) << 4)));
#pragma unroll
            for (int dt = 0; dt < 2; ++dt) {
                int d = dt * 16 + ln15;
                f16x8 vf = *reinterpret_cast<const f16x8*>(reinterpret_cast<char*>(VT) +
                    ((d * 1024 + (jbase + kc * 32 + kgrp * 8) * 2) ^ ((d & 7) << 4)));
                oacc[dt] = __builtin_amdgcn_mfma_f32_16x16x32_f16(pf, vf, oacc[dt], 0, 0, 0);
            }
        }
    }

    {
        float* Op = reinterpret_cast<float*>(reinterpret_cast<char*>(Kh) + wid * 8192);
#pragma unroll
        for (int dt = 0; dt < 2; ++dt)
#pragma unroll
            for (int r = 0; r < 4; ++r)
                Op[(kgrp * 4 + r) * 32 + dt * 16 + ln15] = oacc[dt][r];
        if (ln15 == 0) {
#pragma unroll
            for (int r = 0; r < 4; ++r) {
                Op[512 + kgrp * 4 + r] = m_[r];
                Op[528 + kgrp * 4 + r] = l_[r];
            }
        }
    }
    __syncthreads();

    {
        const int i = tid >> 4, d0 = (tid & 15) * 2;
        float mw[4], M = -3.0e38f;
#pragma unroll
        for (int w = 0; w < 4; ++w) {
            mw[w] = reinterpret_cast<float*>(reinterpret_cast<char*>(Kh) + w * 8192)[512 + i];
            M = fmaxf(M, mw[w]);
        }
        float o0 = 0.f, o1 = 0.f, ls = 0.f;
#pragma unroll
        for (int w = 0; w < 4; ++w) {
            float* Op = reinterpret_cast<float*>(reinterpret_cast<char*>(Kh) + w * 8192);
            float sc = __expf(mw[w] - M);
            ls += Op[528 + i] * sc;
            o0 += Op[i * 32 + d0] * sc;
            o1 += Op[i * 32 + d0 + 1] * sc;
        }
        float inv = 1.0f / ls;
        f16x2 ov; ov[0] = (_Float16)(o0 * inv); ov[1] = (_Float16)(o1 * inv);
        *reinterpret_cast<f16x2*>(&y[(size_t)(b * NNq + i0t + i) * DDm + h * DHh + d0]) = ov;
    }
}

// ---------------------------------------------------------------- launch
extern "C" void kernel_launch(void* const* d_in, const int* in_sizes, int n_in,
                              void* d_out, int out_size, void* d_ws, size_t ws_size,
                              hipStream_t stream) {
    const float* boxes    = (const float*)d_in[0];
    const float* features = (const float*)d_in[1];
    const int*   mask     = (const int*)d_in[2];
    const float* Wq = (const float*)d_in[3];
    const float* bq = (const float*)d_in[4];
    const float* Wk = (const float*)d_in[5];
    const float* bk = (const float*)d_in[6];
    const float* Wv = (const float*)d_in[7];
    const float* bv = (const float*)d_in[8];
    const float* Wo = (const float*)d_in[9];
    const float* bo = (const float*)d_in[10];
    const float* Wg = (const float*)d_in[11];
    const float* bg = (const float*)d_in[12];
    const float* dv = (const float*)d_in[13];

    char* ws = (char*)d_ws;
    __half*    Gb   = (__half*)(ws);                       // 25,165,824
    _Float16*  WT   = (_Float16*)(ws + 25165824);          //  1,572,864
    _Float16*  WgTg = (_Float16*)(ws + 26738688);          //     16,384
    _Float16*  qb   = (_Float16*)(ws + 26755072);          //    524,288
    _Float16*  kb   = (_Float16*)(ws + 27279360);          //    524,288
    _Float16*  vb   = (_Float16*)(ws + 27803648);          //    524,288
    _Float16*  yb   = (_Float16*)(ws + 28327936);          //    524,288
    _Float16*  xh   = (_Float16*)(ws + 28852224);          //    524,288  -> ~29.4 MB
    float*     x    = (float*)d_out;

    k_wcvt<<<dim3(4, 4, 13), dim3(256), 0, stream>>>(Wq, Wk, Wv, Wo, WT, Wg, WgTg);
    k_geo_qkv0<<<dim3(2432), dim3(256), 0, stream>>>(
        boxes, WgTg, bg, dv, mask, Gb,
        features, WT, bq, bk, bv, qb, kb, vb);

    for (int l = 0; l < LLn; ++l) {
        const _Float16* WTq = WT + (size_t)(l * 4 + 0) * 65536;
        const _Float16* WTk = WT + (size_t)(l * 4 + 1) * 65536;
        const _Float16* WTv = WT + (size_t)(l * 4 + 2) * 65536;
        const _Float16* WTo = WT + (size_t)(l * 4 + 3) * 65536;
        const float* bq_l = bq + (size_t)l * DDm;
        const float* bk_l = bk + (size_t)l * DDm;
        const float* bv_l = bv + (size_t)l * DDm;
        const float* bo_l = bo + (size_t)l * DDm;

        if (l > 0) {
            k_gemm_qkv_h<<<dim3(32, 4, 3), dim3(256), 0, stream>>>(
                xh, WTq, WTk, WTv, bq_l, bk_l, bv_l, qb, kb, vb);
        }
        k_attn<<<dim3(32, 16), dim3(256), 0, stream>>>(qb, kb, vb, Gb, yb, l);
        if (l == 0) {
            // resid = features (fp32); out -> xh only
            k_gemm_o<<<dim3(32, 4), dim3(256), 0, stream>>>(
                yb, WTo, bo_l, features, nullptr, nullptr, xh);
        } else if (l == 1) {
            // resid = xh (fp16, in-place); out -> xh only
            k_gemm_o<<<dim3(32, 4), dim3(256), 0, stream>>>(
                yb, WTo, bo_l, nullptr, xh, nullptr, xh);
        } else {
            // final: resid = xh (fp16); out -> fp32 d_out only
            k_gemm_o<<<dim3(32, 4), dim3(256), 0, stream>>>(
                yb, WTo, bo_l, nullptr, xh, x, nullptr);
        }
    }
}

// Round 17
// 100.010 us; speedup vs baseline: 1.0490x; 1.0490x over previous
//
#include <hip/hip_runtime.h>
#include <hip/hip_fp16.h>

// Problem constants (from reference): B=2, N=512, D=256, H=8, L=3
#define BB 2
#define NNq 512
#define DDm 256
#define HHh 8
#define DHh 32
#define LLn 3

static constexpr float EPSF   = 1e-4f;
static constexpr float INV2PI = 0.15915494309189535f;   // 1/(2*pi)
static constexpr float SCALE  = 0.17677669529663687f;   // 1/sqrt(32)

#if __has_builtin(__builtin_amdgcn_fractf)
#define FRACTF(x) __builtin_amdgcn_fractf(x)
#else
#define FRACTF(x) ((x) - floorf(x))
#endif
#if __has_builtin(__builtin_amdgcn_sinf)
#define SINR(x) __builtin_amdgcn_sinf(x)   // sin(2*pi*x), x in revolutions
#define COSR(x) __builtin_amdgcn_cosf(x)
#else
#define SINR(x) __sinf((x) * 6.2831853071795865f)
#define COSR(x) __cosf((x) * 6.2831853071795865f)
#endif
#if __has_builtin(__builtin_amdgcn_rcpf)
#define RCPF(x) __builtin_amdgcn_rcpf(x)
#else
#define RCPF(x) (1.0f / (x))
#endif

typedef _Float16 f16x8 __attribute__((ext_vector_type(8)));
typedef _Float16 f16x4 __attribute__((ext_vector_type(4)));
typedef _Float16 f16x2 __attribute__((ext_vector_type(2)));
typedef float    f32x4 __attribute__((ext_vector_type(4)));

__device__ inline f16x2 pk2(float a, float b) {
#if __has_builtin(__builtin_amdgcn_cvt_pkrtz)
    return __builtin_bit_cast(f16x2, __builtin_amdgcn_cvt_pkrtz(a, b));
#else
    f16x2 r; r[0] = (_Float16)a; r[1] = (_Float16)b; return r;
#endif
}
union U16x8 { f16x8 v; f16x2 h[4]; };

// ---------------------------------------------------------------- weight pre-convert
__global__ __launch_bounds__(256) void k_wcvt(const float* __restrict__ Wq,
        const float* __restrict__ Wk, const float* __restrict__ Wv,
        const float* __restrict__ Wo, _Float16* __restrict__ WT,
        const float* __restrict__ Wg, _Float16* __restrict__ WgTg) {
    __shared__ _Float16 t[64][72];
    const int tid = threadIdx.x;
    const int mat = blockIdx.z;
    if (mat == 12) {
        if (blockIdx.x == 0 && blockIdx.y == 0) {
            for (int idx = tid; idx < 32 * 256; idx += 256) {
                int n = idx >> 8, k = idx & 255;
                float w = (n < 24) ? Wg[(size_t)(n >> 3) * 2048 + (size_t)k * 8 + (n & 7)] : 0.f;
                WgTg[n * 256 + (k ^ ((n & 7) << 3))] = (_Float16)w;
            }
        }
        return;
    }
    const int l = mat >> 2, op = mat & 3;
    const float* W = (op == 0 ? Wq : op == 1 ? Wk : op == 2 ? Wv : Wo)
                     + (size_t)l * 65536;
    const int k0 = blockIdx.x * 64, n0 = blockIdx.y * 64;
    for (int u = tid; u < 64 * 16; u += 256) {
        int k = u >> 4, n4 = (u & 15) * 4;
        float4 w4 = *reinterpret_cast<const float4*>(&W[(size_t)(k0 + k) * 256 + n0 + n4]);
        t[n4 + 0][k] = (_Float16)w4.x; t[n4 + 1][k] = (_Float16)w4.y;
        t[n4 + 2][k] = (_Float16)w4.z; t[n4 + 3][k] = (_Float16)w4.w;
    }
    __syncthreads();
    for (int u = tid; u < 64 * 8; u += 256) {
        int n = u >> 3, kc = (u & 7) * 8;
        *reinterpret_cast<f16x8*>(&WT[((size_t)mat * 256 + n0 + n) * 256 + k0 + kc]) =
            *reinterpret_cast<const f16x8*>(&t[n][kc]);
    }
}

// ---------------------------------------------------------------- fused geo + qkv0
// Blocks 0..2047: geo. Blocks 2048..2431: layer-0 qkv GEMM (LDS-free).
// Round-17: launch_bounds (256,4)->(256,3). The 128-VGPR cap was likely
// spilling the 16 B-fragments (64 VGPR alone) to scratch inside the MFMA
// loop; ~168-VGPR budget keeps them register-resident (12 waves/CU remain).
// Also: Bi box + cxi/cyi/wi/hi hoisted out of the slab loop (all 4 slabs of
// a wave share (b,i): base4 % 4 == 0 so the 64-j span never crosses a row).
__global__ __launch_bounds__(256, 3) void k_geo_qkv0(const float* __restrict__ boxes,
        const _Float16* __restrict__ WgTg, const float* __restrict__ bg,
        const float* __restrict__ divm, const int* __restrict__ maskp,
        __half* __restrict__ G,
        const float* __restrict__ feat, const _Float16* __restrict__ WT,
        const float* __restrict__ bq, const float* __restrict__ bk,
        const float* __restrict__ bv,
        _Float16* __restrict__ qb, _Float16* __restrict__ kb,
        _Float16* __restrict__ vb) {
    __shared__ __half obuf[4][24][68];   // geo part only (13 KB)

    const int tid  = threadIdx.x;
    const int lane = tid & 63;
    const int wid  = tid >> 6;
    const int ln15 = lane & 15;
    const int kgrp = lane >> 4;

    if ((int)blockIdx.x >= 2048) {
        // ---------------- qkv layer-0 (LDS-free) ----------------
        const int q = blockIdx.x - 2048;         // 0..383
        const int z = q >> 7;                    // 0..2
        const int rem = q & 127;
        const int m0 = (rem >> 2) * 32, n0 = (rem & 3) * 64;
        const _Float16* WTz = WT + (size_t)z * 65536;
        const float* bia = (z == 0) ? bq : (z == 1) ? bk : bv;
        _Float16* C = (z == 0) ? qb : (z == 1) ? kb : vb;

        const int mw   = (wid & 1) * 16;
        const int nsel = (wid >> 1) * 16;
        const int kfr  = kgrp * 8;

        const float* Arow = feat + (size_t)(m0 + mw + ln15) * 256;
        const _Float16* W0r = WTz + (size_t)(n0 + nsel + ln15) * 256;
        const _Float16* W1r = WTz + (size_t)(n0 + nsel + 32 + ln15) * 256;

        f32x4 acc[2] = {{0.f,0.f,0.f,0.f},{0.f,0.f,0.f,0.f}};
#pragma unroll
        for (int kc = 0; kc < 8; ++kc) {
            float4 a0 = *reinterpret_cast<const float4*>(Arow + kc * 32 + kfr);
            float4 a1 = *reinterpret_cast<const float4*>(Arow + kc * 32 + kfr + 4);
            U16x8 af;
            af.h[0] = pk2(a0.x, a0.y); af.h[1] = pk2(a0.z, a0.w);
            af.h[2] = pk2(a1.x, a1.y); af.h[3] = pk2(a1.z, a1.w);
            f16x8 b0 = *reinterpret_cast<const f16x8*>(W0r + kc * 32 + kfr);
            f16x8 b1 = *reinterpret_cast<const f16x8*>(W1r + kc * 32 + kfr);
            acc[0] = __builtin_amdgcn_mfma_f32_16x16x32_f16(af.v, b0, acc[0], 0, 0, 0);
            acc[1] = __builtin_amdgcn_mfma_f32_16x16x32_f16(af.v, b1, acc[1], 0, 0, 0);
        }
#pragma unroll
        for (int t = 0; t < 2; ++t) {
            const int col = n0 + nsel + t * 32 + ln15;
            const float bv_ = bia[col];
#pragma unroll
            for (int r = 0; r < 4; ++r) {
                const int row = m0 + mw + kgrp * 4 + r;
                C[(size_t)row * 256 + col] = (_Float16)fmaxf(acc[t][r] + bv_, 0.f);
            }
        }
        return;
    }

    // ---------------- geo ----------------
    float invd[8];
    {
        const float4* dv4 = reinterpret_cast<const float4*>(divm);
        float4 da = dv4[kgrp * 2], db = dv4[kgrp * 2 + 1];
        invd[0] = INV2PI / da.x; invd[1] = INV2PI / da.y;
        invd[2] = INV2PI / da.z; invd[3] = INV2PI / da.w;
        invd[4] = INV2PI / db.x; invd[5] = INV2PI / db.y;
        invd[6] = INV2PI / db.z; invd[7] = INV2PI / db.w;
    }
    const int n0 = ln15;
    const int n1 = 16 + ln15;
    const float bg0 = bg[n0];
    const float bg1 = (n1 < 24) ? bg[n1] : 0.f;

    const int mask  = (ln15 & 7) << 3;
    const int flip5 = mask & 32;
    const int kb_   = (kgrp << 3) ^ (mask & 24);
    const int base0 = n0 * 256 + kb_;
    const int base1 = n1 * 256 + kb_;

    f16x8 bS0[4], bC0[4], bS1[4], bC1[4];
#pragma unroll
    for (int kc2 = 0; kc2 < 4; ++kc2) {
        const int koffS = ((2 * kc2) * 32) ^ flip5;
        const int koffC = ((2 * kc2 + 1) * 32) ^ flip5;
        bS0[kc2] = *reinterpret_cast<const f16x8*>(&WgTg[base0 + koffS]);
        bC0[kc2] = *reinterpret_cast<const f16x8*>(&WgTg[base0 + koffC]);
        bS1[kc2] = *reinterpret_cast<const f16x8*>(&WgTg[base1 + koffS]);
        bC1[kc2] = *reinterpret_cast<const f16x8*>(&WgTg[base1 + koffC]);
    }

    const float4* boxes4 = reinterpret_cast<const float4*>(boxes);
    const size_t plane = (size_t)NNq * NNq;

    const int base4 = (blockIdx.x * 4 + wid) * 4;
    // all 4 slabs share (b,i) (64-j span never crosses a row)
    const int b_  = base4 >> 14;
    const int i_  = (base4 >> 5) & (NNq - 1);
    const int j0b = (base4 & 31) << 4;

    float4 Bi = boxes4[b_ * NNq + i_];
    const float cxi = 0.5f * (Bi.x + Bi.z), cyi = 0.5f * (Bi.y + Bi.w);
    const float wi  = fmaxf(Bi.z - Bi.x, EPSF), hi = fmaxf(Bi.w - Bi.y, EPSF);

#pragma unroll
    for (int it = 0; it < 4; ++it) {
        const int j0 = j0b + it * 16;

        float4 Bj = boxes4[b_ * NNq + j0 + ln15];
        float cxj = 0.5f * (Bj.x + Bj.z), cyj = 0.5f * (Bj.y + Bj.w);
        float wj  = fmaxf(Bj.z - Bj.x, EPSF), hj = fmaxf(Bj.w - Bj.y, EPSF);
        float rwj = RCPF(wj), rhj = RCPF(hj);
        float rel[4];
        rel[0] = __logf(fabsf(cxj - cxi) * rwj + EPSF);
        rel[1] = __logf(fabsf(cyj - cyi) * rhj + EPSF);
        rel[2] = __logf(wi * rwj + EPSF);
        rel[3] = __logf(hi * rhj + EPSF);

        f32x4 acc0 = {0.f, 0.f, 0.f, 0.f};
        f32x4 acc1 = {0.f, 0.f, 0.f, 0.f};

#pragma unroll
        for (int kc2 = 0; kc2 < 4; ++kc2) {
            const float rc = rel[kc2];
            U16x8 afs, afc;
#pragma unroll
            for (int jj = 0; jj < 4; ++jj) {
                float rv0 = FRACTF(rc * invd[2 * jj]);
                float rv1 = FRACTF(rc * invd[2 * jj + 1]);
                afs.h[jj] = pk2(SINR(rv0), SINR(rv1));
                afc.h[jj] = pk2(COSR(rv0), COSR(rv1));
            }
            acc0 = __builtin_amdgcn_mfma_f32_16x16x32_f16(afs.v, bS0[kc2], acc0, 0, 0, 0);
            acc0 = __builtin_amdgcn_mfma_f32_16x16x32_f16(afc.v, bC0[kc2], acc0, 0, 0, 0);
            acc1 = __builtin_amdgcn_mfma_f32_16x16x32_f16(afs.v, bS1[kc2], acc1, 0, 0, 0);
            acc1 = __builtin_amdgcn_mfma_f32_16x16x32_f16(afc.v, bC1[kc2], acc1, 0, 0, 0);
        }

#pragma unroll
        for (int r = 0; r < 4; ++r) {
            const int m = it * 16 + (kgrp << 2) + r;
            float g0 = fmaxf(acc0[r] + bg0, 0.f);
            obuf[wid][n0][m] = __float2half(g0);
            if (n1 < 24) {
                float g1 = fmaxf(acc1[r] + bg1, 0.f);
                obuf[wid][n1][m] = __float2half(g1);
            }
        }
    }
    __syncthreads();

    const int mv  = maskp[((size_t)b_ * NNq + i_) * NNq + j0b + lane];
    size_t obase = (size_t)b_ * plane + (size_t)i_ * NNq + j0b + lane;
#pragma unroll
    for (int t = 0; t < 24; ++t) {
        float g = __half2float(obuf[wid][t][lane]);
        float v = (mv != 0) ? (g + 1e-6f) : 0.0f;
        G[obase + (size_t)t * (BB * plane)] = __float2half(v);
    }
}

// ---------------------------------------------------------------- GEMM qkv (fp16 A, LDS-free)
__global__ __launch_bounds__(256) void k_gemm_qkv_h(const _Float16* __restrict__ A,
        const _Float16* __restrict__ WT0, const _Float16* __restrict__ WT1,
        const _Float16* __restrict__ WT2,
        const float* __restrict__ b0, const float* __restrict__ b1, const float* __restrict__ b2,
        _Float16* __restrict__ C0, _Float16* __restrict__ C1, _Float16* __restrict__ C2) {
    const _Float16* WTz = (blockIdx.z == 0) ? WT0 : (blockIdx.z == 1) ? WT1 : WT2;
    const float*    bia = (blockIdx.z == 0) ? b0 : (blockIdx.z == 1) ? b1 : b2;
    _Float16*       C   = (blockIdx.z == 0) ? C0 : (blockIdx.z == 1) ? C1 : C2;

    const int tid  = threadIdx.x;
    const int lane = tid & 63, wid = tid >> 6;
    const int ln15 = lane & 15, kgrp = lane >> 4;
    const int m0 = blockIdx.x * 32, n0 = blockIdx.y * 64;
    const int mw   = (wid & 1) * 16;
    const int nsel = (wid >> 1) * 16;
    const int kfr  = kgrp * 8;

    const _Float16* Arow = A + (size_t)(m0 + mw + ln15) * 256;
    const _Float16* W0r  = WTz + (size_t)(n0 + nsel + ln15) * 256;
    const _Float16* W1r  = WTz + (size_t)(n0 + nsel + 32 + ln15) * 256;

    f32x4 acc[2] = {{0.f,0.f,0.f,0.f},{0.f,0.f,0.f,0.f}};
#pragma unroll
    for (int kc = 0; kc < 8; ++kc) {
        f16x8 af = *reinterpret_cast<const f16x8*>(Arow + kc * 32 + kfr);
        f16x8 b0_ = *reinterpret_cast<const f16x8*>(W0r + kc * 32 + kfr);
        f16x8 b1_ = *reinterpret_cast<const f16x8*>(W1r + kc * 32 + kfr);
        acc[0] = __builtin_amdgcn_mfma_f32_16x16x32_f16(af, b0_, acc[0], 0, 0, 0);
        acc[1] = __builtin_amdgcn_mfma_f32_16x16x32_f16(af, b1_, acc[1], 0, 0, 0);
    }
#pragma unroll
    for (int t = 0; t < 2; ++t) {
        const int col = n0 + nsel + t * 32 + ln15;
        const float bv = bia[col];
#pragma unroll
        for (int r = 0; r < 4; ++r) {
            const int row = m0 + mw + kgrp * 4 + r;
            C[(size_t)row * 256 + col] = (_Float16)fmaxf(acc[t][r] + bv, 0.f);
        }
    }
}

// ---------------------------------------------------------------- GEMM o (LDS-free; dual fp32+fp16 out)
__global__ __launch_bounds__(256) void k_gemm_o(const _Float16* __restrict__ A,
        const _Float16* __restrict__ WT0, const float* __restrict__ bia,
        float* __restrict__ C, _Float16* __restrict__ Ch,
        const float* __restrict__ resid) {
    const int tid  = threadIdx.x;
    const int lane = tid & 63, wid = tid >> 6;
    const int ln15 = lane & 15, kgrp = lane >> 4;
    const int m0 = blockIdx.x * 32, n0 = blockIdx.y * 64;
    const int mw   = (wid & 1) * 16;
    const int nsel = (wid >> 1) * 16;
    const int kfr  = kgrp * 8;

    const _Float16* Arow = A + (size_t)(m0 + mw + ln15) * 256;
    const _Float16* W0r  = WT0 + (size_t)(n0 + nsel + ln15) * 256;
    const _Float16* W1r  = WT0 + (size_t)(n0 + nsel + 32 + ln15) * 256;

    f32x4 acc[2] = {{0.f,0.f,0.f,0.f},{0.f,0.f,0.f,0.f}};
#pragma unroll
    for (int kc = 0; kc < 8; ++kc) {
        f16x8 af = *reinterpret_cast<const f16x8*>(Arow + kc * 32 + kfr);
        f16x8 b0_ = *reinterpret_cast<const f16x8*>(W0r + kc * 32 + kfr);
        f16x8 b1_ = *reinterpret_cast<const f16x8*>(W1r + kc * 32 + kfr);
        acc[0] = __builtin_amdgcn_mfma_f32_16x16x32_f16(af, b0_, acc[0], 0, 0, 0);
        acc[1] = __builtin_amdgcn_mfma_f32_16x16x32_f16(af, b1_, acc[1], 0, 0, 0);
    }
#pragma unroll
    for (int t = 0; t < 2; ++t) {
        const int col = n0 + nsel + t * 32 + ln15;
        const float bv = bia[col];
#pragma unroll
        for (int r = 0; r < 4; ++r) {
            const int row = m0 + mw + kgrp * 4 + r;
            float o = fmaxf(acc[t][r] + bv, 0.f) + resid[(size_t)row * 256 + col];
            C[(size_t)row * 256 + col] = o;
            Ch[(size_t)row * 256 + col] = (_Float16)o;
        }
    }
}

// ---------------------------------------------------------------- fused attention (MFMA v2, multiplicative geo)
__global__ __launch_bounds__(256) void k_attn(const _Float16* __restrict__ q,
                                              const _Float16* __restrict__ kk,
                                              const _Float16* __restrict__ vv,
                                              const __half* __restrict__ G,
                                              _Float16* __restrict__ y, int l) {
    __shared__ _Float16 Kh[512 * 32];   // 32 KB, row j: 64B, swz ((j&7)<<4)
    __shared__ _Float16 VT[32 * 512];   // 32 KB, row d: 1KB, swz ((d&7)<<4)
    __shared__ _Float16 Ps[4][16 * 128];// 16 KB, per-wave, swz ((i&7)<<4)

    const int bh = blockIdx.y;
    const int b = bh >> 3, h = bh & 7;
    const int i0t = blockIdx.x * 16;

    const int tid  = threadIdx.x;
    const int lane = tid & 63, wid = tid >> 6;
    const int ln15 = lane & 15, kgrp = lane >> 4;

    for (int u = tid; u < 2048; u += 256) {
        int j = u >> 2, d8 = (u & 3) * 8;
        const size_t src = (size_t)(b * NNq + j) * DDm + h * DHh + d8;
        f16x8 kv = *reinterpret_cast<const f16x8*>(&kk[src]);
        *reinterpret_cast<f16x8*>(reinterpret_cast<char*>(Kh) +
            ((j * 64 + d8 * 2) ^ ((j & 7) << 4))) = kv;
        f16x8 v8 = *reinterpret_cast<const f16x8*>(&vv[src]);
#pragma unroll
        for (int e = 0; e < 8; ++e) {
            int row = d8 + e;
            *reinterpret_cast<_Float16*>(reinterpret_cast<char*>(VT) +
                ((row * 1024 + j * 2) ^ ((row & 7) << 4))) = v8[e];
        }
    }

    f16x8 qf = *reinterpret_cast<const f16x8*>(
        &q[(size_t)(b * NNq + i0t + ln15) * DDm + h * DHh + kgrp * 8]);
    __syncthreads();

    const int jbase = wid * 128;
    const size_t plane = (size_t)NNq * NNq;
    const size_t g_base = (size_t)((l * 8 + h) * BB + b) * plane;

    f32x4 s[8];
#pragma unroll
    for (int t = 0; t < 8; ++t) {
        int j = jbase + t * 16 + ln15;
        f16x8 kf = *reinterpret_cast<const f16x8*>(reinterpret_cast<char*>(Kh) +
            ((j * 64 + kgrp * 16) ^ ((j & 7) << 4)));
        f32x4 z = {0.f, 0.f, 0.f, 0.f};
        s[t] = __builtin_amdgcn_mfma_f32_16x16x32_f16(qf, kf, z, 0, 0, 0);
    }

    float gv[8][4];
#pragma unroll
    for (int t = 0; t < 8; ++t) {
        const size_t jg = jbase + t * 16 + ln15;
#pragma unroll
        for (int r = 0; r < 4; ++r)
            gv[t][r] = __half2float(G[g_base + (size_t)(i0t + kgrp * 4 + r) * NNq + jg]);
    }

    float m_[4], l_[4];
#pragma unroll
    for (int r = 0; r < 4; ++r) {
        float mx = s[0][r];
#pragma unroll
        for (int t = 1; t < 8; ++t) mx = fmaxf(mx, s[t][r]);
        mx *= SCALE;
#pragma unroll
        for (int o = 1; o < 16; o <<= 1) mx = fmaxf(mx, __shfl_xor(mx, o, 64));
        float sum = 0.f;
#pragma unroll
        for (int t = 0; t < 8; ++t) {
            float p = gv[t][r] * __expf(s[t][r] * SCALE - mx);
            s[t][r] = p; sum += p;
        }
#pragma unroll
        for (int o = 1; o < 16; o <<= 1) sum += __shfl_xor(sum, o, 64);
        m_[r] = mx; l_[r] = sum;
    }

    {
        char* psb = reinterpret_cast<char*>(Ps[wid]);
#pragma unroll
        for (int r = 0; r < 4; ++r) {
            const int row = kgrp * 4 + r;
            const int rb = row * 256, sw = (row & 7) << 4;
#pragma unroll
            for (int t = 0; t < 8; ++t) {
                int byte = (rb + (t * 16 + ln15) * 2) ^ sw;
                *reinterpret_cast<_Float16*>(psb + byte) = (_Float16)s[t][r];
            }
        }
    }

    f32x4 oacc[2] = {{0.f,0.f,0.f,0.f},{0.f,0.f,0.f,0.f}};
    {
        char* psb = reinterpret_cast<char*>(Ps[wid]);
#pragma unroll
        for (int kc = 0; kc < 4; ++kc) {
            f16x8 pf = *reinterpret_cast<const f16x8*>(psb +
                ((ln15 * 256 + kc * 64 + kgrp * 16) ^ ((ln15 & 7) << 4)));
#pragma unroll
            for (int dt = 0; dt < 2; ++dt) {
                int d = dt * 16 + ln15;
                f16x8 vf = *reinterpret_cast<const f16x8*>(reinterpret_cast<char*>(VT) +
                    ((d * 1024 + (jbase + kc * 32 + kgrp * 8) * 2) ^ ((d & 7) << 4)));
                oacc[dt] = __builtin_amdgcn_mfma_f32_16x16x32_f16(pf, vf, oacc[dt], 0, 0, 0);
            }
        }
    }

    {
        float* Op = reinterpret_cast<float*>(reinterpret_cast<char*>(Kh) + wid * 8192);
#pragma unroll
        for (int dt = 0; dt < 2; ++dt)
#pragma unroll
            for (int r = 0; r < 4; ++r)
                Op[(kgrp * 4 + r) * 32 + dt * 16 + ln15] = oacc[dt][r];
        if (ln15 == 0) {
#pragma unroll
            for (int r = 0; r < 4; ++r) {
                Op[512 + kgrp * 4 + r] = m_[r];
                Op[528 + kgrp * 4 + r] = l_[r];
            }
        }
    }
    __syncthreads();

    {
        const int i = tid >> 4, d0 = (tid & 15) * 2;
        float mw[4], M = -3.0e38f;
#pragma unroll
        for (int w = 0; w < 4; ++w) {
            mw[w] = reinterpret_cast<float*>(reinterpret_cast<char*>(Kh) + w * 8192)[512 + i];
            M = fmaxf(M, mw[w]);
        }
        float o0 = 0.f, o1 = 0.f, ls = 0.f;
#pragma unroll
        for (int w = 0; w < 4; ++w) {
            float* Op = reinterpret_cast<float*>(reinterpret_cast<char*>(Kh) + w * 8192);
            float sc = __expf(mw[w] - M);
            ls += Op[528 + i] * sc;
            o0 += Op[i * 32 + d0] * sc;
            o1 += Op[i * 32 + d0 + 1] * sc;
        }
        float inv = 1.0f / ls;
        f16x2 ov; ov[0] = (_Float16)(o0 * inv); ov[1] = (_Float16)(o1 * inv);
        *reinterpret_cast<f16x2*>(&y[(size_t)(b * NNq + i0t + i) * DDm + h * DHh + d0]) = ov;
    }
}

// ---------------------------------------------------------------- launch
extern "C" void kernel_launch(void* const* d_in, const int* in_sizes, int n_in,
                              void* d_out, int out_size, void* d_ws, size_t ws_size,
                              hipStream_t stream) {
    const float* boxes    = (const float*)d_in[0];
    const float* features = (const float*)d_in[1];
    const int*   mask     = (const int*)d_in[2];
    const float* Wq = (const float*)d_in[3];
    const float* bq = (const float*)d_in[4];
    const float* Wk = (const float*)d_in[5];
    const float* bk = (const float*)d_in[6];
    const float* Wv = (const float*)d_in[7];
    const float* bv = (const float*)d_in[8];
    const float* Wo = (const float*)d_in[9];
    const float* bo = (const float*)d_in[10];
    const float* Wg = (const float*)d_in[11];
    const float* bg = (const float*)d_in[12];
    const float* dv = (const float*)d_in[13];

    char* ws = (char*)d_ws;
    __half*    Gb   = (__half*)(ws);                       // 25,165,824
    _Float16*  WT   = (_Float16*)(ws + 25165824);          //  1,572,864
    _Float16*  WgTg = (_Float16*)(ws + 26738688);          //     16,384
    _Float16*  qb   = (_Float16*)(ws + 26755072);          //    524,288
    _Float16*  kb   = (_Float16*)(ws + 27279360);          //    524,288
    _Float16*  vb   = (_Float16*)(ws + 27803648);          //    524,288
    _Float16*  yb   = (_Float16*)(ws + 28327936);          //    524,288
    _Float16*  xh   = (_Float16*)(ws + 28852224);          //    524,288  -> ~29.4 MB
    float*     x    = (float*)d_out;

    k_wcvt<<<dim3(4, 4, 13), dim3(256), 0, stream>>>(Wq, Wk, Wv, Wo, WT, Wg, WgTg);
    k_geo_qkv0<<<dim3(2432), dim3(256), 0, stream>>>(
        boxes, WgTg, bg, dv, mask, Gb,
        features, WT, bq, bk, bv, qb, kb, vb);

    for (int l = 0; l < LLn; ++l) {
        const _Float16* WTq = WT + (size_t)(l * 4 + 0) * 65536;
        const _Float16* WTk = WT + (size_t)(l * 4 + 1) * 65536;
        const _Float16* WTv = WT + (size_t)(l * 4 + 2) * 65536;
        const _Float16* WTo = WT + (size_t)(l * 4 + 3) * 65536;
        const float* bq_l = bq + (size_t)l * DDm;
        const float* bk_l = bk + (size_t)l * DDm;
        const float* bv_l = bv + (size_t)l * DDm;
        const float* bo_l = bo + (size_t)l * DDm;

        if (l > 0) {
            k_gemm_qkv_h<<<dim3(32, 4, 3), dim3(256), 0, stream>>>(
                xh, WTq, WTk, WTv, bq_l, bk_l, bv_l, qb, kb, vb);
        }
        k_attn<<<dim3(32, 16), dim3(256), 0, stream>>>(qb, kb, vb, Gb, yb, l);
        if (l == 0) {
            k_gemm_o<<<dim3(32, 4), dim3(256), 0, stream>>>(
                yb, WTo, bo_l, x, xh, features);
        } else {
            k_gemm_o<<<dim3(32, 4), dim3(256), 0, stream>>>(
                yb, WTo, bo_l, x, xh, x);
        }
    }
}